// Round 8
// baseline (181.018 us; speedup 1.0000x reference)
//
#include <hip/hip_runtime.h>
#include <hip/hip_bf16.h>

typedef short short8 __attribute__((ext_vector_type(8)));
typedef float float4v __attribute__((ext_vector_type(4)));

// ws layout: [0, 32KB) = We2 in bf16 MFMA-B-fragment order (16384 shorts)
//            float* F = (float*)ws + 8192, offsets below (in floats)
#define WS_T   0        // T[21][128]
#define WS_D   2688     // be2+bl2+br2+cr0
#define WS_C   2816     // cl0
#define WS_O   2944     // bl2+bo2
#define WS_A2  3072     // a2
#define WS_KEY 3200     // decoding-order keys[4096]
#define WS_G   7296     // G[21][21] = W_out^T @ T^T rows (21x21)
#define WS_B0  7744     // b_out + W_out^T @ O   (21)
#define WS_B1  7776     // W_out^T @ cl0         (21)

__device__ __forceinline__ unsigned int pack2bf(float a, float b) {
  // two fp32 -> packed bf16 pair (round-half-up; differs from RNE only on ties)
  union { float f; unsigned int u; } xa, xb;
  xa.f = a; xb.f = b;
  return ((xa.u + 0x8000u) >> 16) | ((xb.u + 0x8000u) & 0xFFFF0000u);
}

// ---------------------------------------------------------------------------
// Prologue 1 (grid 38 x 256): block 0 = We2 swizzle (bf16, B-frag order) +
// collapsed constants; blocks 1..21 = T[v] = W_s[v] @ Wl2[128:,:];
// blocks 22..37 = decoding-order keys.
// ---------------------------------------------------------------------------
__global__ __launch_bounds__(256) void pg8_pre(
    const float* __restrict__ Wl2, const float* __restrict__ Wr2,
    const float* __restrict__ We2, const float* __restrict__ bl1,
    const float* __restrict__ bl2, const float* __restrict__ br2,
    const float* __restrict__ be2, const float* __restrict__ a2,
    const float* __restrict__ bo1, const float* __restrict__ bo2,
    const float* __restrict__ W_s, const float* __restrict__ mask,
    const float* __restrict__ chain_M, const float* __restrict__ z,
    void* __restrict__ ws)
{
  short* wsW = (short*)ws;
  float* F = (float*)ws + 8192;
  const int b = blockIdx.x, tid = threadIdx.x;
  if (b == 0) {
    for (int s = tid; s < 16384; s += 256) {
      const int row = s >> 7, c = s & 127;            // row = K idx, c = N idx
      const int q = row >> 5, lh = (row & 31) >> 3, j = row & 7;
      const int t = c >> 4, cl = c & 15;
      union { float f; unsigned int u; } x; x.f = We2[s];
      const unsigned int r = x.u + 0x7FFFu + ((x.u >> 16) & 1u);  // RNE
      wsW[(((q * 8 + t) * 64) + lh * 16 + cl) * 8 + j] = (short)(r >> 16);
    }
    if (tid < 128) {
      const int c = tid;
      float cl0 = 0.f, cr0 = 0.f;
      for (int i = 0; i < 128; i++) {
        const float s = bl1[i] + bo1[i];     // layer-1 output (constant vector)
        cl0 += s * Wl2[i * 128 + c];
        cr0 += s * Wr2[i * 128 + c];
      }
      F[WS_D + c]  = be2[c] + bl2[c] + br2[c] + cr0;
      F[WS_C + c]  = cl0;
      F[WS_O + c]  = bl2[c] + bo2[c];
      F[WS_A2 + c] = a2[c];
    }
  } else if (b <= 21) {
    const int v = b - 1;
    if (tid < 128) {
      const int c = tid;
      float acc = 0.f;
      for (int h = 0; h < 128; h++)
        acc += W_s[v * 128 + h] * Wl2[(128 + h) * 128 + c];
      F[WS_T + v * 128 + c] = acc;
    }
  } else {
    const int n = (b - 22) * 256 + tid;
    F[WS_KEY + n] = (chain_M[n] * mask[n] + 1e-4f) * fabsf(z[n]);
  }
}

// ---------------------------------------------------------------------------
// Prologue 2 (grid 2 x 256, after pre1): fold T / O / cl0 through W_out:
//   G[v][u]  = sum_c T[v][c]  * W_out[c*21+u]
//   base0[u] = b_out[u] + sum_c O[c] * W_out[c*21+u]
//   base1[u] = sum_c cl0[c] * W_out[c*21+u]
// ---------------------------------------------------------------------------
__global__ __launch_bounds__(256) void pg8_pre2(
    const float* __restrict__ W_out, const float* __restrict__ b_out,
    void* __restrict__ ws)
{
  float* F = (float*)ws + 8192;
  const int idx = blockIdx.x * 256 + threadIdx.x;
  if (idx < 441) {
    const int v = idx / 21, u = idx % 21;
    float acc = 0.f;
    for (int c = 0; c < 128; c++)
      acc += F[WS_T + v * 128 + c] * W_out[c * 21 + u];
    F[WS_G + v * 21 + u] = acc;
  } else if (idx < 462) {
    const int u = idx - 441;
    float acc = b_out[u];
    for (int c = 0; c < 128; c++)
      acc += F[WS_O + c] * W_out[c * 21 + u];
    F[WS_B0 + u] = acc;
  } else if (idx < 483) {
    const int u = idx - 462;
    float acc = 0.f;
    for (int c = 0; c < 128; c++)
      acc += F[WS_C + c] * W_out[c * 21 + u];
    F[WS_B1 + u] = acc;
  }
}

// ---------------------------------------------------------------------------
// Main (grid 1024 x 256): one wave per node, zero block-wide barriers.
// B-frags/T/consts/G stream from L2-hot ws; LDS = 1KB wave-private edge meta.
// logits[u] = base0[u] + maskn*base1[u] + sum_k coef_k * G[S_k][u].
// ---------------------------------------------------------------------------
__global__ __launch_bounds__(256, 4) void pg8_main(
    const float* __restrict__ E, const int* __restrict__ E_idx,
    const int* __restrict__ S, const float* __restrict__ mask,
    const void* __restrict__ ws, float* __restrict__ out)
{
  __shared__ float ldswk[4][32];     // wave-private edge meta
  __shared__ int   ldsrv[4][32];

  const short* wsW = (const short*)ws;
  const float* F = (const float*)ws + 8192;
  const int tid  = threadIdx.x;
  const int wave = tid >> 6;
  const int lane = tid & 63;
  const int quad = lane >> 4;
  const int lid  = lane & 15;
  const int n    = blockIdx.x * 4 + wave;
  const float maskn = mask[n];

  // --- edge meta (wave-private LDS broadcast; DS is in-order per wave)
  if (lane < 32) {
    const int j = E_idx[n * 32 + lane];
    const float keyn = F[WS_KEY + n], kj = F[WS_KEY + j];
    // stable argsort: j ordered before n  <=>  (key[j], j) <lex (key[n], n)
    const int before = (kj < keyn) || (kj == keyn && j < n);
    ldswk[wave][lane] = before ? maskn : 0.f;
    ldsrv[wave][lane] = S[j];
  }
  __builtin_amdgcn_wave_barrier();

  // --- A fragments: A[m=lid][k = q*32 + quad*8 + j]
  short8 afr[2][4];
#pragma unroll
  for (int g = 0; g < 2; g++) {
    const float* erow = E + (size_t)(n * 32 + g * 16 + lid) * 128 + quad * 8;
#pragma unroll
    for (int q = 0; q < 4; q++) {
      const float4 A = *(const float4*)(erow + q * 32);
      const float4 B = *(const float4*)(erow + q * 32 + 4);
      union { short8 s; unsigned int u[4]; } v;
      v.u[0] = pack2bf(A.x, A.y);
      v.u[1] = pack2bf(A.z, A.w);
      v.u[2] = pack2bf(B.x, B.y);
      v.u[3] = pack2bf(B.z, B.w);
      afr[g][q] = v.s;
    }
  }

  int rows[2][4]; float wks[2][4];
#pragma unroll
  for (int g = 0; g < 2; g++)
#pragma unroll
    for (int r = 0; r < 4; r++) {
      const int kk = g * 16 + quad * 4 + r;
      rows[g][r] = ldsrv[wave][kk] * 128;
      wks[g][r]  = ldswk[wave][kk];
    }

  // --- K-loop: load each B tile once, feed both edge groups
  float part[2][4] = {{0.f, 0.f, 0.f, 0.f}, {0.f, 0.f, 0.f, 0.f}};
#pragma unroll
  for (int t = 0; t < 8; t++) {
    short8 bfr[4];
#pragma unroll
    for (int q = 0; q < 4; q++)
      bfr[q] = *(const short8*)(wsW + (((q * 8 + t) * 64) + lane) * 8);
    float4v ac0 = {0.f, 0.f, 0.f, 0.f}, ac1 = {0.f, 0.f, 0.f, 0.f};
#pragma unroll
    for (int q = 0; q < 4; q++) {
      ac0 = __builtin_amdgcn_mfma_f32_16x16x32_bf16(afr[0][q], bfr[q], ac0, 0, 0, 0);
      ac1 = __builtin_amdgcn_mfma_f32_16x16x32_bf16(afr[1][q], bfr[q], ac1, 0, 0, 0);
    }
    const int c = t * 16 + lid;
    const float dvt  = F[WS_D + c] + maskn * F[WS_C + c];
    const float a2vt = F[WS_A2 + c];
#pragma unroll
    for (int r = 0; r < 4; r++) {
      float v0 = ac0[r] + dvt + wks[0][r] * F[WS_T + rows[0][r] + c];
      float v1 = ac1[r] + dvt + wks[1][r] * F[WS_T + rows[1][r] + c];
      v0 = fmaxf(v0, 0.f) + 0.2f * fminf(v0, 0.f);   // leaky_relu(0.2)
      v1 = fmaxf(v1, 0.f) + 0.2f * fminf(v1, 0.f);
      part[0][r] = fmaf(v0, a2vt, part[0][r]);
      part[1][r] = fmaf(v1, a2vt, part[1][r]);
    }
  }
  // reduce scores over the 16 c-lanes of each quad
  float sreg[2][4];
#pragma unroll
  for (int g = 0; g < 2; g++)
#pragma unroll
    for (int r = 0; r < 4; r++) {
      float v = part[g][r];
      v += __shfl_xor(v, 1);
      v += __shfl_xor(v, 2);
      v += __shfl_xor(v, 4);
      v += __shfl_xor(v, 8);
      sreg[g][r] = v;   // score for edge kk = g*16 + quad*4 + r (uniform in quad)
    }

  // --- softmax over 32 neighbor scores
  float mx = -1e30f;
#pragma unroll
  for (int g = 0; g < 2; g++)
#pragma unroll
    for (int r = 0; r < 4; r++) mx = fmaxf(mx, sreg[g][r]);
  mx = fmaxf(mx, __shfl_xor(mx, 16));
  mx = fmaxf(mx, __shfl_xor(mx, 32));
  float eg[2][4], esum = 0.f;
#pragma unroll
  for (int g = 0; g < 2; g++)
#pragma unroll
    for (int r = 0; r < 4; r++) {
      eg[g][r] = expf(sreg[g][r] - mx);
      esum += eg[g][r];
    }
  esum += __shfl_xor(esum, 16);
  esum += __shfl_xor(esum, 32);
  const float inv = 1.f / esum;
  float cg[2][4];
#pragma unroll
  for (int g = 0; g < 2; g++)
#pragma unroll
    for (int r = 0; r < 4; r++) cg[g][r] = eg[g][r] * inv * wks[g][r];

  // --- logits via 21x21 table: lg[u] = base0 + maskn*base1 + sum_k cf_k*G[S_k][u]
  float lg = (lane < 21) ? (F[WS_B0 + lane] + maskn * F[WS_B1 + lane]) : -1e30f;
#pragma unroll
  for (int kk = 0; kk < 32; kk++) {
    const int g = kk >> 4, sq = (kk >> 2) & 3, r = kk & 3;
    const float cf = __shfl(cg[g][r], sq * 16);   // broadcast from source quad
    const int row = ldsrv[wave][kk] * 21;         // same-addr LDS read: broadcast
    if (lane < 21) lg = fmaf(cf, F[WS_G + row + lane], lg);
  }

  // --- log_softmax over V=21
  float lmx = lg;
  lmx = fmaxf(lmx, __shfl_xor(lmx, 1));
  lmx = fmaxf(lmx, __shfl_xor(lmx, 2));
  lmx = fmaxf(lmx, __shfl_xor(lmx, 4));
  lmx = fmaxf(lmx, __shfl_xor(lmx, 8));
  lmx = fmaxf(lmx, __shfl_xor(lmx, 16));
  float ex = (lane < 21) ? expf(lg - lmx) : 0.f;
  float es = ex;
  es += __shfl_xor(es, 1);
  es += __shfl_xor(es, 2);
  es += __shfl_xor(es, 4);
  es += __shfl_xor(es, 8);
  es += __shfl_xor(es, 16);
  if (lane < 21)
    out[n * 21 + lane] = lg - lmx - logf(es);
}

extern "C" void kernel_launch(void* const* d_in, const int* in_sizes, int n_in,
                              void* d_out, int out_size, void* d_ws, size_t ws_size,
                              hipStream_t stream)
{
  const float* E       = (const float*)d_in[0];
  const int*   E_idx   = (const int*)d_in[1];
  const int*   S       = (const int*)d_in[2];
  const float* mask    = (const float*)d_in[3];
  const float* chain_M = (const float*)d_in[4];
  const float* z       = (const float*)d_in[5];
  const float* bl1     = (const float*)d_in[7];
  const float* bo1     = (const float*)d_in[13];
  const float* Wl2     = (const float*)d_in[14];
  const float* bl2     = (const float*)d_in[15];
  const float* Wr2     = (const float*)d_in[16];
  const float* br2     = (const float*)d_in[17];
  const float* We2     = (const float*)d_in[18];
  const float* be2     = (const float*)d_in[19];
  const float* a2      = (const float*)d_in[20];
  const float* bo2     = (const float*)d_in[21];
  const float* W_s     = (const float*)d_in[22];
  const float* W_out   = (const float*)d_in[23];
  const float* b_out   = (const float*)d_in[24];

  pg8_pre<<<38, 256, 0, stream>>>(Wl2, Wr2, We2, bl1, bl2, br2, be2, a2,
                                  bo1, bo2, W_s, mask, chain_M, z, d_ws);
  pg8_pre2<<<2, 256, 0, stream>>>(W_out, b_out, d_ws);
  pg8_main<<<1024, 256, 0, stream>>>(E, E_idx, S, mask, d_ws, (float*)d_out);
}

// Round 9
// 172.764 us; speedup vs baseline: 1.0478x; 1.0478x over previous
//
#include <hip/hip_runtime.h>
#include <hip/hip_bf16.h>

typedef short short8 __attribute__((ext_vector_type(8)));
typedef float float4v __attribute__((ext_vector_type(4)));

// ws layout: [0, 32KB) = We2 in bf16 MFMA-B-fragment order (16384 shorts)
//            float* F = (float*)ws + 8192, offsets below (in floats)
#define WS_T   0        // T[21][128]
#define WS_D   2688     // be2+bl2+br2+cr0
#define WS_C   2816     // cl0
#define WS_O   2944     // bl2+bo2
#define WS_A2  3072     // a2
#define WS_KEY 3200     // decoding-order keys[4096]
#define WS_G   7296     // G[21][21] = rows of T folded through W_out
#define WS_B0  7744     // b_out + W_out^T @ O   (21)
#define WS_B1  7776     // W_out^T @ cl0         (21)

__device__ __forceinline__ unsigned int pack2bf(float a, float b) {
  // two fp32 -> packed bf16 pair (round-half-up; differs from RNE only on ties)
  union { float f; unsigned int u; } xa, xb;
  xa.f = a; xb.f = b;
  return ((xa.u + 0x8000u) >> 16) | ((xb.u + 0x8000u) & 0xFFFF0000u);
}

// ---------------------------------------------------------------------------
// Merged prologue (grid 38 x 256):
//  block 0      : We2 swizzle (bf16 B-frag order) + collapsed constants,
//                 then base0/base1 (constants folded through W_out)
//  blocks 1..21 : T[v] = W_s[v] @ Wl2[128:,:]  then  G[v] = W_out^T T[v]
//  blocks 22..37: decoding-order keys
// ---------------------------------------------------------------------------
__global__ __launch_bounds__(256) void pg9_pre(
    const float* __restrict__ Wl2, const float* __restrict__ Wr2,
    const float* __restrict__ We2, const float* __restrict__ bl1,
    const float* __restrict__ bl2, const float* __restrict__ br2,
    const float* __restrict__ be2, const float* __restrict__ a2,
    const float* __restrict__ bo1, const float* __restrict__ bo2,
    const float* __restrict__ W_s, const float* __restrict__ mask,
    const float* __restrict__ chain_M, const float* __restrict__ z,
    const float* __restrict__ W_out, const float* __restrict__ b_out,
    void* __restrict__ ws)
{
  __shared__ float sA[128], sB[128];
  short* wsW = (short*)ws;
  float* F = (float*)ws + 8192;
  const int b = blockIdx.x, tid = threadIdx.x;
  if (b == 0) {
    for (int s = tid; s < 16384; s += 256) {
      const int row = s >> 7, c = s & 127;            // row = K idx, c = N idx
      const int q = row >> 5, lh = (row & 31) >> 3, j = row & 7;
      const int t = c >> 4, cl = c & 15;
      union { float f; unsigned int u; } x; x.f = We2[s];
      const unsigned int r = x.u + 0x7FFFu + ((x.u >> 16) & 1u);  // RNE
      wsW[(((q * 8 + t) * 64) + lh * 16 + cl) * 8 + j] = (short)(r >> 16);
    }
    if (tid < 128) {
      const int c = tid;
      float cl0 = 0.f, cr0 = 0.f;
      for (int i = 0; i < 128; i++) {
        const float s = bl1[i] + bo1[i];     // layer-1 output (constant vector)
        cl0 += s * Wl2[i * 128 + c];
        cr0 += s * Wr2[i * 128 + c];
      }
      const float O = bl2[c] + bo2[c];
      F[WS_D + c]  = be2[c] + bl2[c] + br2[c] + cr0;
      F[WS_C + c]  = cl0;
      F[WS_O + c]  = O;
      F[WS_A2 + c] = a2[c];
      sA[c] = O;
      sB[c] = cl0;
    }
    __syncthreads();
    if (tid < 21) {
      float b0 = b_out[tid], b1 = 0.f;
      for (int c = 0; c < 128; c++) {
        b0 = fmaf(sA[c], W_out[c * 21 + tid], b0);
        b1 = fmaf(sB[c], W_out[c * 21 + tid], b1);
      }
      F[WS_B0 + tid] = b0;
      F[WS_B1 + tid] = b1;
    }
  } else if (b <= 21) {
    const int v = b - 1;
    if (tid < 128) {
      const int c = tid;
      float acc = 0.f;
      for (int h = 0; h < 128; h++)
        acc += W_s[v * 128 + h] * Wl2[(128 + h) * 128 + c];
      F[WS_T + v * 128 + c] = acc;
      sA[c] = acc;
    }
    __syncthreads();
    if (tid < 21) {
      float g = 0.f;
      for (int c = 0; c < 128; c++)
        g = fmaf(sA[c], W_out[c * 21 + tid], g);
      F[WS_G + v * 21 + tid] = g;
    }
  } else {
    const int n = (b - 22) * 256 + tid;
    F[WS_KEY + n] = (chain_M[n] * mask[n] + 1e-4f) * fabsf(z[n]);
  }
}

// ---------------------------------------------------------------------------
// Main (grid 1024 x 256): one wave per node, ZERO LDS, zero barriers.
// Edge meta redistributed via __shfl from lanes 0..31. B-frags/T/consts/G
// stream from L2-hot ws. logits via the 21x21 G table.
// ---------------------------------------------------------------------------
__global__ __launch_bounds__(256, 4) void pg9_main(
    const float* __restrict__ E, const int* __restrict__ E_idx,
    const int* __restrict__ S, const float* __restrict__ mask,
    const void* __restrict__ ws, float* __restrict__ out)
{
  const short* wsW = (const short*)ws;
  const float* F = (const float*)ws + 8192;
  const int tid  = threadIdx.x;
  const int wave = tid >> 6;
  const int lane = tid & 63;
  const int quad = lane >> 4;
  const int lid  = lane & 15;
  const int n    = blockIdx.x * 4 + wave;
  const float maskn = mask[n];

  // --- A fragments first (longest-latency loads): A[m=lid][k=q*32+quad*8+j]
  short8 afr[2][4];
#pragma unroll
  for (int g = 0; g < 2; g++) {
    const float* erow = E + (size_t)(n * 32 + g * 16 + lid) * 128 + quad * 8;
#pragma unroll
    for (int q = 0; q < 4; q++) {
      const float4 A = *(const float4*)(erow + q * 32);
      const float4 B = *(const float4*)(erow + q * 32 + 4);
      union { short8 s; unsigned int u[4]; } v;
      v.u[0] = pack2bf(A.x, A.y);
      v.u[1] = pack2bf(A.z, A.w);
      v.u[2] = pack2bf(B.x, B.y);
      v.u[3] = pack2bf(B.z, B.w);
      afr[g][q] = v.s;
    }
  }

  // --- edge meta on lanes 0..31, redistributed by shuffle (no LDS)
  float wkv = 0.f; int rvv = 0;
  if (lane < 32) {
    const int j = E_idx[n * 32 + lane];
    const float keyn = F[WS_KEY + n], kj = F[WS_KEY + j];
    // stable argsort: j ordered before n  <=>  (key[j], j) <lex (key[n], n)
    const int before = (kj < keyn) || (kj == keyn && j < n);
    wkv = before ? maskn : 0.f;
    rvv = S[j];
  }
  int rows[2][4]; float wks[2][4];
#pragma unroll
  for (int g = 0; g < 2; g++)
#pragma unroll
    for (int r = 0; r < 4; r++) {
      const int kk = g * 16 + quad * 4 + r;
      rows[g][r] = __shfl(rvv, kk) * 128;
      wks[g][r]  = __shfl(wkv, kk);
    }

  // --- K-loop: load each B tile once, feed both edge groups
  float part[2][4] = {{0.f, 0.f, 0.f, 0.f}, {0.f, 0.f, 0.f, 0.f}};
#pragma unroll
  for (int t = 0; t < 8; t++) {
    short8 bfr[4];
#pragma unroll
    for (int q = 0; q < 4; q++)
      bfr[q] = *(const short8*)(wsW + (((q * 8 + t) * 64) + lane) * 8);
    float4v ac0 = {0.f, 0.f, 0.f, 0.f}, ac1 = {0.f, 0.f, 0.f, 0.f};
#pragma unroll
    for (int q = 0; q < 4; q++) {
      ac0 = __builtin_amdgcn_mfma_f32_16x16x32_bf16(afr[0][q], bfr[q], ac0, 0, 0, 0);
      ac1 = __builtin_amdgcn_mfma_f32_16x16x32_bf16(afr[1][q], bfr[q], ac1, 0, 0, 0);
    }
    const int c = t * 16 + lid;
    const float dvt  = F[WS_D + c] + maskn * F[WS_C + c];
    const float a2vt = F[WS_A2 + c];
#pragma unroll
    for (int r = 0; r < 4; r++) {
      float v0 = ac0[r] + dvt + wks[0][r] * F[WS_T + rows[0][r] + c];
      float v1 = ac1[r] + dvt + wks[1][r] * F[WS_T + rows[1][r] + c];
      v0 = fmaxf(v0, 0.f) + 0.2f * fminf(v0, 0.f);   // leaky_relu(0.2)
      v1 = fmaxf(v1, 0.f) + 0.2f * fminf(v1, 0.f);
      part[0][r] = fmaf(v0, a2vt, part[0][r]);
      part[1][r] = fmaf(v1, a2vt, part[1][r]);
    }
  }
  // reduce scores over the 16 c-lanes of each quad
  float sreg[2][4];
#pragma unroll
  for (int g = 0; g < 2; g++)
#pragma unroll
    for (int r = 0; r < 4; r++) {
      float v = part[g][r];
      v += __shfl_xor(v, 1);
      v += __shfl_xor(v, 2);
      v += __shfl_xor(v, 4);
      v += __shfl_xor(v, 8);
      sreg[g][r] = v;   // score for edge kk = g*16 + quad*4 + r (uniform in quad)
    }

  // --- softmax over 32 neighbor scores
  float mx = -1e30f;
#pragma unroll
  for (int g = 0; g < 2; g++)
#pragma unroll
    for (int r = 0; r < 4; r++) mx = fmaxf(mx, sreg[g][r]);
  mx = fmaxf(mx, __shfl_xor(mx, 16));
  mx = fmaxf(mx, __shfl_xor(mx, 32));
  float eg[2][4], esum = 0.f;
#pragma unroll
  for (int g = 0; g < 2; g++)
#pragma unroll
    for (int r = 0; r < 4; r++) {
      eg[g][r] = expf(sreg[g][r] - mx);
      esum += eg[g][r];
    }
  esum += __shfl_xor(esum, 16);
  esum += __shfl_xor(esum, 32);
  const float inv = 1.f / esum;
  float cg[2][4];
#pragma unroll
  for (int g = 0; g < 2; g++)
#pragma unroll
    for (int r = 0; r < 4; r++) cg[g][r] = eg[g][r] * inv * wks[g][r];

  // --- logits via 21x21 table: lg[u] = base0 + maskn*base1 + sum_k cf_k*G[S_k][u]
  float lg = (lane < 21) ? (F[WS_B0 + lane] + maskn * F[WS_B1 + lane]) : -1e30f;
#pragma unroll
  for (int kk = 0; kk < 32; kk++) {
    const int g = kk >> 4, sq = (kk >> 2) & 3, r = kk & 3;
    const float cf = __shfl(cg[g][r], sq * 16);   // broadcast from source quad
    const int row = __shfl(rvv, kk) * 21;         // edge's S value from lane kk
    if (lane < 21) lg = fmaf(cf, F[WS_G + row + lane], lg);
  }

  // --- log_softmax over V=21
  float lmx = lg;
  lmx = fmaxf(lmx, __shfl_xor(lmx, 1));
  lmx = fmaxf(lmx, __shfl_xor(lmx, 2));
  lmx = fmaxf(lmx, __shfl_xor(lmx, 4));
  lmx = fmaxf(lmx, __shfl_xor(lmx, 8));
  lmx = fmaxf(lmx, __shfl_xor(lmx, 16));
  float ex = (lane < 21) ? expf(lg - lmx) : 0.f;
  float es = ex;
  es += __shfl_xor(es, 1);
  es += __shfl_xor(es, 2);
  es += __shfl_xor(es, 4);
  es += __shfl_xor(es, 8);
  es += __shfl_xor(es, 16);
  if (lane < 21)
    out[n * 21 + lane] = lg - lmx - logf(es);
}

extern "C" void kernel_launch(void* const* d_in, const int* in_sizes, int n_in,
                              void* d_out, int out_size, void* d_ws, size_t ws_size,
                              hipStream_t stream)
{
  const float* E       = (const float*)d_in[0];
  const int*   E_idx   = (const int*)d_in[1];
  const int*   S       = (const int*)d_in[2];
  const float* mask    = (const float*)d_in[3];
  const float* chain_M = (const float*)d_in[4];
  const float* z       = (const float*)d_in[5];
  const float* bl1     = (const float*)d_in[7];
  const float* bo1     = (const float*)d_in[13];
  const float* Wl2     = (const float*)d_in[14];
  const float* bl2     = (const float*)d_in[15];
  const float* Wr2     = (const float*)d_in[16];
  const float* br2     = (const float*)d_in[17];
  const float* We2     = (const float*)d_in[18];
  const float* be2     = (const float*)d_in[19];
  const float* a2      = (const float*)d_in[20];
  const float* bo2     = (const float*)d_in[21];
  const float* W_s     = (const float*)d_in[22];
  const float* W_out   = (const float*)d_in[23];
  const float* b_out   = (const float*)d_in[24];

  pg9_pre<<<38, 256, 0, stream>>>(Wl2, Wr2, We2, bl1, bl2, br2, be2, a2,
                                  bo1, bo2, W_s, mask, chain_M, z,
                                  W_out, b_out, d_ws);
  pg9_main<<<1024, 256, 0, stream>>>(E, E_idx, S, mask, d_ws, (float*)d_out);
}

// Round 10
// 168.178 us; speedup vs baseline: 1.0763x; 1.0273x over previous
//
#include <hip/hip_runtime.h>
#include <hip/hip_bf16.h>

typedef short short8 __attribute__((ext_vector_type(8)));
typedef float float4v __attribute__((ext_vector_type(4)));

// ws layout: [0, 32KB) = We2 in bf16 MFMA-B-fragment order (16384 shorts)
//            float* F = (float*)ws + 8192, offsets below (in floats)
#define WS_T   0        // T[21][128]
#define WS_D   2688     // be2+bl2+br2+cr0
#define WS_C   2816     // cl0
#define WS_O   2944     // bl2+bo2
#define WS_A2  3072     // a2
#define WS_G   7296     // G[21][21] = rows of T folded through W_out
#define WS_B0  7744     // b_out + W_out^T @ O   (21)
#define WS_B1  7776     // W_out^T @ cl0         (21)
#define WS_M   7808     // packed per-node meta: float2 { key[n], bitcast S[n] }

__device__ __forceinline__ unsigned int pack2bf(float a, float b) {
  // two fp32 -> packed bf16 pair (round-half-up; differs from RNE only on ties)
  union { float f; unsigned int u; } xa, xb;
  xa.f = a; xb.f = b;
  return ((xa.u + 0x8000u) >> 16) | ((xb.u + 0x8000u) & 0xFFFF0000u);
}

// ---------------------------------------------------------------------------
// Merged prologue (grid 38 x 256):
//  block 0      : We2 swizzle (bf16 B-frag order) + collapsed constants +
//                 base0/base1 (constants folded through W_out)
//  blocks 1..21 : T[v] = W_s[v] @ Wl2[128:,:]  then  G[v] = W_out^T T[v]
//  blocks 22..37: packed meta M[n] = (decoding key[n], S[n])
// ---------------------------------------------------------------------------
__global__ __launch_bounds__(256) void pg10_pre(
    const float* __restrict__ Wl2, const float* __restrict__ Wr2,
    const float* __restrict__ We2, const float* __restrict__ bl1,
    const float* __restrict__ bl2, const float* __restrict__ br2,
    const float* __restrict__ be2, const float* __restrict__ a2,
    const float* __restrict__ bo1, const float* __restrict__ bo2,
    const float* __restrict__ W_s, const float* __restrict__ mask,
    const float* __restrict__ chain_M, const float* __restrict__ z,
    const int* __restrict__ S, const float* __restrict__ W_out,
    const float* __restrict__ b_out, void* __restrict__ ws)
{
  __shared__ float sA[128], sB[128];
  short* wsW = (short*)ws;
  float* F = (float*)ws + 8192;
  const int b = blockIdx.x, tid = threadIdx.x;
  if (b == 0) {
    for (int s = tid; s < 16384; s += 256) {
      const int row = s >> 7, c = s & 127;            // row = K idx, c = N idx
      const int q = row >> 5, lh = (row & 31) >> 3, j = row & 7;
      const int t = c >> 4, cl = c & 15;
      union { float f; unsigned int u; } x; x.f = We2[s];
      const unsigned int r = x.u + 0x7FFFu + ((x.u >> 16) & 1u);  // RNE
      wsW[(((q * 8 + t) * 64) + lh * 16 + cl) * 8 + j] = (short)(r >> 16);
    }
    if (tid < 128) {
      const int c = tid;
      float cl0 = 0.f, cr0 = 0.f;
      for (int i = 0; i < 128; i++) {
        const float s = bl1[i] + bo1[i];     // layer-1 output (constant vector)
        cl0 += s * Wl2[i * 128 + c];
        cr0 += s * Wr2[i * 128 + c];
      }
      const float O = bl2[c] + bo2[c];
      F[WS_D + c]  = be2[c] + bl2[c] + br2[c] + cr0;
      F[WS_C + c]  = cl0;
      F[WS_O + c]  = O;
      F[WS_A2 + c] = a2[c];
      sA[c] = O;
      sB[c] = cl0;
    }
    __syncthreads();
    if (tid < 21) {
      float b0 = b_out[tid], b1 = 0.f;
      for (int c = 0; c < 128; c++) {
        b0 = fmaf(sA[c], W_out[c * 21 + tid], b0);
        b1 = fmaf(sB[c], W_out[c * 21 + tid], b1);
      }
      F[WS_B0 + tid] = b0;
      F[WS_B1 + tid] = b1;
    }
  } else if (b <= 21) {
    const int v = b - 1;
    if (tid < 128) {
      const int c = tid;
      float acc = 0.f;
      for (int h = 0; h < 128; h++)
        acc += W_s[v * 128 + h] * Wl2[(128 + h) * 128 + c];
      F[WS_T + v * 128 + c] = acc;
      sA[c] = acc;
    }
    __syncthreads();
    if (tid < 21) {
      float g = 0.f;
      for (int c = 0; c < 128; c++)
        g = fmaf(sA[c], W_out[c * 21 + tid], g);
      F[WS_G + v * 21 + tid] = g;
    }
  } else {
    const int n = (b - 22) * 256 + tid;
    F[WS_M + 2 * n] = (chain_M[n] * mask[n] + 1e-4f) * fabsf(z[n]);
    ((int*)F)[WS_M + 2 * n + 1] = S[n];
  }
}

// ---------------------------------------------------------------------------
// Main (grid 1024 x 256): one wave per node, wave-private LDS E-staging.
// E streamed with COALESCED float4 loads (16 lines/instr vs 64 for the old
// row-gather), packed bf16 into LDS (row stride 136 shorts -> 2-way-only
// read conflicts), fragments via ds_read_b128. Zero block-wide barriers.
// ---------------------------------------------------------------------------
__global__ __launch_bounds__(256, 4) void pg10_main(
    const float* __restrict__ E, const int* __restrict__ E_idx,
    const float* __restrict__ mask, const void* __restrict__ ws,
    float* __restrict__ out)
{
  __shared__ __align__(16) short ldsE[4][32 * 136];   // 8704 B per wave

  const short* wsW = (const short*)ws;
  const float* F = (const float*)ws + 8192;
  const int tid  = threadIdx.x;
  const int wave = tid >> 6;
  const int lane = tid & 63;
  const int quad = lane >> 4;
  const int lid  = lane & 15;
  const int n    = blockIdx.x * 4 + wave;
  const float maskn = mask[n];

  // --- edge meta first (heads the longest dependent chain): E_idx -> M[j]
  int jidx = 0;
  if (lane < 32) jidx = E_idx[n * 32 + lane];

  // --- coalesced E staging: 16 KB fp32 -> 8 KB bf16 in wave-private LDS
  const float* ebase = E + (size_t)n * 32 * 128;
  short* myE = ldsE[wave];
#pragma unroll
  for (int i = 0; i < 8; i++) {
    const int e = i * 512 + lane * 8;          // element index, consecutive 32B/lane
    const float4 A = *(const float4*)(ebase + e);
    const float4 B = *(const float4*)(ebase + e + 4);
    union { short8 s; unsigned int u[4]; } v;
    v.u[0] = pack2bf(A.x, A.y);
    v.u[1] = pack2bf(A.z, A.w);
    v.u[2] = pack2bf(B.x, B.y);
    v.u[3] = pack2bf(B.z, B.w);
    *(short8*)(myE + (e >> 7) * 136 + (e & 127)) = v.s;
  }

  // --- finish meta: one packed float2 gather per edge
  float wkv = 0.f; int rvv = 0;
  const float keyn = F[WS_M + 2 * n];
  if (lane < 32) {
    const float2 mj = *(const float2*)(F + WS_M + 2 * jidx);
    // stable argsort: j ordered before n  <=>  (key[j], j) <lex (key[n], n)
    const int before = (mj.x < keyn) || (mj.x == keyn && jidx < n);
    wkv = before ? maskn : 0.f;
    union { float f; int i; } c; c.f = mj.y; rvv = c.i;
  }
  int rows[2][4]; float wks[2][4];
#pragma unroll
  for (int g = 0; g < 2; g++)
#pragma unroll
    for (int r = 0; r < 4; r++) {
      const int kk = g * 16 + quad * 4 + r;
      rows[g][r] = __shfl(rvv, kk) * 128;
      wks[g][r]  = __shfl(wkv, kk);
    }

  __builtin_amdgcn_wave_barrier();

  // --- A fragments from LDS: A[m=lid][k = q*32 + quad*8 + j]
  short8 afr[2][4];
#pragma unroll
  for (int g = 0; g < 2; g++)
#pragma unroll
    for (int q = 0; q < 4; q++)
      afr[g][q] = *(const short8*)(myE + (g * 16 + lid) * 136 + q * 32 + quad * 8);

  // --- K-loop: load each B tile once, feed both edge groups
  float part[2][4] = {{0.f, 0.f, 0.f, 0.f}, {0.f, 0.f, 0.f, 0.f}};
#pragma unroll
  for (int t = 0; t < 8; t++) {
    short8 bfr[4];
#pragma unroll
    for (int q = 0; q < 4; q++)
      bfr[q] = *(const short8*)(wsW + (((q * 8 + t) * 64) + lane) * 8);
    float4v ac0 = {0.f, 0.f, 0.f, 0.f}, ac1 = {0.f, 0.f, 0.f, 0.f};
#pragma unroll
    for (int q = 0; q < 4; q++) {
      ac0 = __builtin_amdgcn_mfma_f32_16x16x32_bf16(afr[0][q], bfr[q], ac0, 0, 0, 0);
      ac1 = __builtin_amdgcn_mfma_f32_16x16x32_bf16(afr[1][q], bfr[q], ac1, 0, 0, 0);
    }
    const int c = t * 16 + lid;
    const float dvt  = F[WS_D + c] + maskn * F[WS_C + c];
    const float a2vt = F[WS_A2 + c];
#pragma unroll
    for (int r = 0; r < 4; r++) {
      float v0 = ac0[r] + dvt + wks[0][r] * F[WS_T + rows[0][r] + c];
      float v1 = ac1[r] + dvt + wks[1][r] * F[WS_T + rows[1][r] + c];
      v0 = fmaxf(v0, 0.f) + 0.2f * fminf(v0, 0.f);   // leaky_relu(0.2)
      v1 = fmaxf(v1, 0.f) + 0.2f * fminf(v1, 0.f);
      part[0][r] = fmaf(v0, a2vt, part[0][r]);
      part[1][r] = fmaf(v1, a2vt, part[1][r]);
    }
  }
  // reduce scores over the 16 c-lanes of each quad
  float sreg[2][4];
#pragma unroll
  for (int g = 0; g < 2; g++)
#pragma unroll
    for (int r = 0; r < 4; r++) {
      float v = part[g][r];
      v += __shfl_xor(v, 1);
      v += __shfl_xor(v, 2);
      v += __shfl_xor(v, 4);
      v += __shfl_xor(v, 8);
      sreg[g][r] = v;   // score for edge kk = g*16 + quad*4 + r (uniform in quad)
    }

  // --- softmax over 32 neighbor scores
  float mx = -1e30f;
#pragma unroll
  for (int g = 0; g < 2; g++)
#pragma unroll
    for (int r = 0; r < 4; r++) mx = fmaxf(mx, sreg[g][r]);
  mx = fmaxf(mx, __shfl_xor(mx, 16));
  mx = fmaxf(mx, __shfl_xor(mx, 32));
  float eg[2][4], esum = 0.f;
#pragma unroll
  for (int g = 0; g < 2; g++)
#pragma unroll
    for (int r = 0; r < 4; r++) {
      eg[g][r] = expf(sreg[g][r] - mx);
      esum += eg[g][r];
    }
  esum += __shfl_xor(esum, 16);
  esum += __shfl_xor(esum, 32);
  const float inv = 1.f / esum;
  float cg[2][4];
#pragma unroll
  for (int g = 0; g < 2; g++)
#pragma unroll
    for (int r = 0; r < 4; r++) cg[g][r] = eg[g][r] * inv * wks[g][r];

  // --- logits via 21x21 table: lg[u] = base0 + maskn*base1 + sum_k cf_k*G[S_k][u]
  float lg = (lane < 21) ? (F[WS_B0 + lane] + maskn * F[WS_B1 + lane]) : -1e30f;
#pragma unroll
  for (int kk = 0; kk < 32; kk++) {
    const int g = kk >> 4, sq = (kk >> 2) & 3, r = kk & 3;
    const float cf = __shfl(cg[g][r], sq * 16);     // broadcast from source quad
    const int row = (rows[0][0], __shfl(rvv, kk)) * 21;  // edge's S from lane kk
    if (lane < 21) lg = fmaf(cf, F[WS_G + row + lane], lg);
  }

  // --- log_softmax over V=21
  float lmx = lg;
  lmx = fmaxf(lmx, __shfl_xor(lmx, 1));
  lmx = fmaxf(lmx, __shfl_xor(lmx, 2));
  lmx = fmaxf(lmx, __shfl_xor(lmx, 4));
  lmx = fmaxf(lmx, __shfl_xor(lmx, 8));
  lmx = fmaxf(lmx, __shfl_xor(lmx, 16));
  float ex = (lane < 21) ? expf(lg - lmx) : 0.f;
  float es = ex;
  es += __shfl_xor(es, 1);
  es += __shfl_xor(es, 2);
  es += __shfl_xor(es, 4);
  es += __shfl_xor(es, 8);
  es += __shfl_xor(es, 16);
  if (lane < 21)
    out[n * 21 + lane] = lg - lmx - logf(es);
}

extern "C" void kernel_launch(void* const* d_in, const int* in_sizes, int n_in,
                              void* d_out, int out_size, void* d_ws, size_t ws_size,
                              hipStream_t stream)
{
  const float* E       = (const float*)d_in[0];
  const int*   E_idx   = (const int*)d_in[1];
  const int*   S       = (const int*)d_in[2];
  const float* mask    = (const float*)d_in[3];
  const float* chain_M = (const float*)d_in[4];
  const float* z       = (const float*)d_in[5];
  const float* bl1     = (const float*)d_in[7];
  const float* bo1     = (const float*)d_in[13];
  const float* Wl2     = (const float*)d_in[14];
  const float* bl2     = (const float*)d_in[15];
  const float* Wr2     = (const float*)d_in[16];
  const float* br2     = (const float*)d_in[17];
  const float* We2     = (const float*)d_in[18];
  const float* be2     = (const float*)d_in[19];
  const float* a2      = (const float*)d_in[20];
  const float* bo2     = (const float*)d_in[21];
  const float* W_s     = (const float*)d_in[22];
  const float* W_out   = (const float*)d_in[23];
  const float* b_out   = (const float*)d_in[24];

  pg10_pre<<<38, 256, 0, stream>>>(Wl2, Wr2, We2, bl1, bl2, br2, be2, a2,
                                   bo1, bo2, W_s, mask, chain_M, z, S,
                                   W_out, b_out, d_ws);
  pg10_main<<<1024, 256, 0, stream>>>(E, E_idx, mask, d_ws, (float*)d_out);
}